// Round 1
// baseline (267.221 us; speedup 1.0000x reference)
//
#include <hip/hip_runtime.h>
#include <hip/hip_bf16.h>
#include <stdint.h>

#define T_TOKENS 8192
#define F_DIM    2048
#define E_EXP    16
#define R_RANK   16
#define O_DIM    2048
#define KDIM     (E_EXP * R_RANK)   // 256

typedef short v8s __attribute__((ext_vector_type(8)));
typedef float v4f __attribute__((ext_vector_type(4)));

__device__ __forceinline__ uint16_t f2bf(float f) {
  uint32_t u = __builtin_bit_cast(uint32_t, f);
  u += 0x7fffu + ((u >> 16) & 1u);   // round-to-nearest-even
  return (uint16_t)(u >> 16);
}

// ---------------------------------------------------------------------------
// K0: cast A_stack (E,R,F)=(256,2048) -> bf16 flat; gather-transpose B_stack
// (E,O,R) -> Bb (O, K=E*R) K-major bf16.
// ---------------------------------------------------------------------------
__global__ __launch_bounds__(256) void prep_weights(
    const float* __restrict__ A, const float* __restrict__ Bst,
    uint16_t* __restrict__ Ab, uint16_t* __restrict__ Bb) {
  int idx = blockIdx.x * 256 + threadIdx.x;
  if (idx < KDIM * F_DIM) {
    Ab[idx] = f2bf(A[idx]);
  }
  if (idx < O_DIM * KDIM) {
    int k = idx & (KDIM - 1);
    int o = idx >> 8;
    int e = k >> 4, r = k & 15;
    Bb[idx] = f2bf(Bst[((size_t)e * O_DIM + o) * R_RANK + r]);
  }
}

// ---------------------------------------------------------------------------
// K1: fused x->bf16 conversion + fp32(chunk)/fp64(accum) routing sim +
// top-k + softmax (*scaling) -> coeffS (8192 x 16 fp32, zeros off top-k).
// Block: 256 thr, 32 tokens. Thread computes 2 tokens x 1 expert.
// ---------------------------------------------------------------------------
__global__ __launch_bounds__(256) void route_convert(
    const float* __restrict__ x, const float* __restrict__ P,
    const float* __restrict__ scaling, const int* __restrict__ topk,
    uint16_t* __restrict__ xb, float* __restrict__ coeffS) {
  __shared__ float xs[32][68];
  __shared__ float ps[16][68];
  __shared__ double sim_s[32][16];

  const int tid = threadIdx.x;
  const int t0  = blockIdx.x * 32;
  const int lr  = tid >> 3;            // 0..31
  const int lc  = (tid & 7) * 8;       // 0..56
  const int pr  = tid >> 4;            // 0..15
  const int pc  = (tid & 15) * 4;      // 0..60
  const int tg  = tid & 15;
  const int e   = tid >> 4;            // 0..15
  const int ta  = 2 * tg, tb = 2 * tg + 1;

  double accA = 0.0, accB = 0.0;

  for (int f0 = 0; f0 < F_DIM; f0 += 64) {
    const size_t xoff = (size_t)(t0 + lr) * F_DIM + f0 + lc;
    float4 xv0 = *(const float4*)&x[xoff];
    float4 xv1 = *(const float4*)&x[xoff + 4];
    *(float4*)&xs[lr][lc]     = xv0;
    *(float4*)&xs[lr][lc + 4] = xv1;
    union { uint16_t s[8]; uint4 u; } cv;
    cv.s[0] = f2bf(xv0.x); cv.s[1] = f2bf(xv0.y);
    cv.s[2] = f2bf(xv0.z); cv.s[3] = f2bf(xv0.w);
    cv.s[4] = f2bf(xv1.x); cv.s[5] = f2bf(xv1.y);
    cv.s[6] = f2bf(xv1.z); cv.s[7] = f2bf(xv1.w);
    *(uint4*)&xb[xoff] = cv.u;
    *(float4*)&ps[pr][pc] = *(const float4*)&P[(size_t)pr * F_DIM + f0 + pc];
    __syncthreads();

    float ca = 0.f, cb = 0.f;
    #pragma unroll
    for (int f = 0; f < 64; f += 4) {
      float4 xa = *(float4*)&xs[ta][f];
      float4 xc = *(float4*)&xs[tb][f];
      float4 pv = *(float4*)&ps[e][f];
      ca += xa.x * pv.x; ca += xa.y * pv.y; ca += xa.z * pv.z; ca += xa.w * pv.w;
      cb += xc.x * pv.x; cb += xc.y * pv.y; cb += xc.z * pv.z; cb += xc.w * pv.w;
    }
    accA += (double)ca;
    accB += (double)cb;
    __syncthreads();
  }

  sim_s[ta][e] = fabs(accA);
  sim_s[tb][e] = fabs(accB);
  __syncthreads();

  if (tid < 32) {
    const int t = t0 + tid;
    double v[16];
    #pragma unroll
    for (int j = 0; j < 16; j++) v[j] = sim_s[tid][j];
    int k = topk[0];
    if (k > 16) k = 16;
    if (k < 1)  k = 1;
    int sel[16];
    double sv[16];
    bool used[16];
    #pragma unroll
    for (int j = 0; j < 16; j++) used[j] = false;
    for (int i = 0; i < k; i++) {
      int bj = 0; double bv = -1.0;
      for (int j = 0; j < 16; j++) {
        if (!used[j] && v[j] > bv) { bv = v[j]; bj = j; }
      }
      used[bj] = true; sel[i] = bj; sv[i] = bv;
    }
    double m = sv[0];
    double s = 0.0;
    double ex[16];
    for (int i = 0; i < k; i++) { ex[i] = exp(sv[i] - m); s += ex[i]; }
    float co[16];
    #pragma unroll
    for (int j = 0; j < 16; j++) co[j] = 0.f;
    const float sc = scaling[0];
    for (int i = 0; i < k; i++) co[sel[i]] = (float)(ex[i] / s) * sc;
    #pragma unroll
    for (int j = 0; j < 16; j++) coeffS[(size_t)t * 16 + j] = co[j];
  }
}

// ---------------------------------------------------------------------------
// K2: z = xb (8192x2048) @ Ab^T (256x2048, K-major)  [bf16 MFMA 16x16x32]
// Epilogue: w = z * coeffS[t][n>>4]  -> wb bf16 (8192 x 256).
// Block 64x64 tile, BK=64, 4 waves in 2x2, each wave 32x32 (2x2 MFMA tiles).
// ---------------------------------------------------------------------------
__global__ __launch_bounds__(256) void gemm_xa(
    const uint16_t* __restrict__ xb, const uint16_t* __restrict__ Ab,
    const float* __restrict__ coeffS, uint16_t* __restrict__ wb) {
  __shared__ uint16_t Xs[64][72];
  __shared__ uint16_t As[64][72];
  const int tid  = threadIdx.x;
  const int n0   = blockIdx.x * 64;
  const int m0   = blockIdx.y * 64;
  const int lane = tid & 63;
  const int wid  = tid >> 6;
  const int wm   = (wid >> 1) * 32;
  const int wn   = (wid & 1) * 32;
  const int quad = lane >> 4;
  const int cl   = lane & 15;
  const int lr   = tid >> 3;
  const int lc   = (tid & 7) * 8;

  v4f acc[2][2];
  #pragma unroll
  for (int i = 0; i < 2; i++)
    #pragma unroll
    for (int j = 0; j < 2; j++) acc[i][j] = (v4f){0.f, 0.f, 0.f, 0.f};

  for (int k0 = 0; k0 < F_DIM; k0 += 64) {
    *(uint4*)&Xs[lr][lc]      = *(const uint4*)&xb[(size_t)(m0 + lr) * F_DIM + k0 + lc];
    *(uint4*)&Xs[lr + 32][lc] = *(const uint4*)&xb[(size_t)(m0 + lr + 32) * F_DIM + k0 + lc];
    *(uint4*)&As[lr][lc]      = *(const uint4*)&Ab[(size_t)(n0 + lr) * F_DIM + k0 + lc];
    *(uint4*)&As[lr + 32][lc] = *(const uint4*)&Ab[(size_t)(n0 + lr + 32) * F_DIM + k0 + lc];
    __syncthreads();
    #pragma unroll
    for (int ks = 0; ks < 64; ks += 32) {
      v8s a0 = *(v8s*)&Xs[wm + cl][ks + quad * 8];
      v8s a1 = *(v8s*)&Xs[wm + 16 + cl][ks + quad * 8];
      v8s b0 = *(v8s*)&As[wn + cl][ks + quad * 8];
      v8s b1 = *(v8s*)&As[wn + 16 + cl][ks + quad * 8];
      acc[0][0] = __builtin_amdgcn_mfma_f32_16x16x32_bf16(a0, b0, acc[0][0], 0, 0, 0);
      acc[0][1] = __builtin_amdgcn_mfma_f32_16x16x32_bf16(a0, b1, acc[0][1], 0, 0, 0);
      acc[1][0] = __builtin_amdgcn_mfma_f32_16x16x32_bf16(a1, b0, acc[1][0], 0, 0, 0);
      acc[1][1] = __builtin_amdgcn_mfma_f32_16x16x32_bf16(a1, b1, acc[1][1], 0, 0, 0);
    }
    __syncthreads();
  }

  #pragma unroll
  for (int mi = 0; mi < 2; mi++)
    #pragma unroll
    for (int ni = 0; ni < 2; ni++) {
      const int n = n0 + wn + ni * 16 + cl;
      const int eidx = n >> 4;
      #pragma unroll
      for (int reg = 0; reg < 4; reg++) {
        const int t = m0 + wm + mi * 16 + quad * 4 + reg;
        float wv = acc[mi][ni][reg] * coeffS[(size_t)t * 16 + eidx];
        wb[(size_t)t * KDIM + n] = f2bf(wv);
      }
    }
}

// ---------------------------------------------------------------------------
// K3: out = wb (8192x256) @ Bb^T (2048x256, K-major) -> fp32 out.
// Same structure as K2, K=256 (4 iterations).
// ---------------------------------------------------------------------------
__global__ __launch_bounds__(256) void gemm_wb(
    const uint16_t* __restrict__ wb, const uint16_t* __restrict__ Bb,
    float* __restrict__ out) {
  __shared__ uint16_t Ws[64][72];
  __shared__ uint16_t Bs[64][72];
  const int tid  = threadIdx.x;
  const int n0   = blockIdx.x * 64;
  const int m0   = blockIdx.y * 64;
  const int lane = tid & 63;
  const int wid  = tid >> 6;
  const int wm   = (wid >> 1) * 32;
  const int wn   = (wid & 1) * 32;
  const int quad = lane >> 4;
  const int cl   = lane & 15;
  const int lr   = tid >> 3;
  const int lc   = (tid & 7) * 8;

  v4f acc[2][2];
  #pragma unroll
  for (int i = 0; i < 2; i++)
    #pragma unroll
    for (int j = 0; j < 2; j++) acc[i][j] = (v4f){0.f, 0.f, 0.f, 0.f};

  for (int k0 = 0; k0 < KDIM; k0 += 64) {
    *(uint4*)&Ws[lr][lc]      = *(const uint4*)&wb[(size_t)(m0 + lr) * KDIM + k0 + lc];
    *(uint4*)&Ws[lr + 32][lc] = *(const uint4*)&wb[(size_t)(m0 + lr + 32) * KDIM + k0 + lc];
    *(uint4*)&Bs[lr][lc]      = *(const uint4*)&Bb[(size_t)(n0 + lr) * KDIM + k0 + lc];
    *(uint4*)&Bs[lr + 32][lc] = *(const uint4*)&Bb[(size_t)(n0 + lr + 32) * KDIM + k0 + lc];
    __syncthreads();
    #pragma unroll
    for (int ks = 0; ks < 64; ks += 32) {
      v8s a0 = *(v8s*)&Ws[wm + cl][ks + quad * 8];
      v8s a1 = *(v8s*)&Ws[wm + 16 + cl][ks + quad * 8];
      v8s b0 = *(v8s*)&Bs[wn + cl][ks + quad * 8];
      v8s b1 = *(v8s*)&Bs[wn + 16 + cl][ks + quad * 8];
      acc[0][0] = __builtin_amdgcn_mfma_f32_16x16x32_bf16(a0, b0, acc[0][0], 0, 0, 0);
      acc[0][1] = __builtin_amdgcn_mfma_f32_16x16x32_bf16(a0, b1, acc[0][1], 0, 0, 0);
      acc[1][0] = __builtin_amdgcn_mfma_f32_16x16x32_bf16(a1, b0, acc[1][0], 0, 0, 0);
      acc[1][1] = __builtin_amdgcn_mfma_f32_16x16x32_bf16(a1, b1, acc[1][1], 0, 0, 0);
    }
    __syncthreads();
  }

  #pragma unroll
  for (int mi = 0; mi < 2; mi++)
    #pragma unroll
    for (int ni = 0; ni < 2; ni++) {
      const int o = n0 + wn + ni * 16 + cl;
      #pragma unroll
      for (int reg = 0; reg < 4; reg++) {
        const int t = m0 + wm + mi * 16 + quad * 4 + reg;
        out[(size_t)t * O_DIM + o] = acc[mi][ni][reg];
      }
    }
}

extern "C" void kernel_launch(void* const* d_in, const int* in_sizes, int n_in,
                              void* d_out, int out_size, void* d_ws, size_t ws_size,
                              hipStream_t stream) {
  (void)in_sizes; (void)n_in; (void)out_size; (void)ws_size;
  const float* x       = (const float*)d_in[0];
  const float* P       = (const float*)d_in[1];
  const float* A       = (const float*)d_in[2];
  const float* Bst     = (const float*)d_in[3];
  const float* scaling = (const float*)d_in[4];
  const int*   topk    = (const int*)d_in[5];
  float* out = (float*)d_out;

  char* ws = (char*)d_ws;
  uint16_t* xb     = (uint16_t*)(ws);                 // 33,554,432 B
  uint16_t* Ab     = (uint16_t*)(ws + 33554432);      //  1,048,576 B
  uint16_t* Bb     = (uint16_t*)(ws + 34603008);      //  1,048,576 B
  uint16_t* wbuf   = (uint16_t*)(ws + 35651584);      //  4,194,304 B
  float*    coeffS = (float*)   (ws + 39845888);      //    524,288 B

  hipLaunchKernelGGL(prep_weights, dim3(2048), dim3(256), 0, stream, A, Bst, Ab, Bb);
  hipLaunchKernelGGL(route_convert, dim3(T_TOKENS / 32), dim3(256), 0, stream,
                     x, P, scaling, topk, xb, coeffS);
  hipLaunchKernelGGL(gemm_xa, dim3(KDIM / 64, T_TOKENS / 64), dim3(256), 0, stream,
                     xb, Ab, coeffS, wbuf);
  hipLaunchKernelGGL(gemm_wb, dim3(O_DIM / 64, T_TOKENS / 64), dim3(256), 0, stream,
                     wbuf, Bb, out);
}

// Round 2
// 203.387 us; speedup vs baseline: 1.3139x; 1.3139x over previous
//
#include <hip/hip_runtime.h>
#include <hip/hip_bf16.h>
#include <stdint.h>

#define T_TOKENS 8192
#define F_DIM    2048
#define E_EXP    16
#define R_RANK   16
#define O_DIM    2048
#define KDIM     (E_EXP * R_RANK)   // 256

typedef short v8s __attribute__((ext_vector_type(8)));
typedef float v4f __attribute__((ext_vector_type(4)));

#define AS1 __attribute__((address_space(1)))
#define AS3 __attribute__((address_space(3)))

__device__ __forceinline__ uint16_t f2bf(float f) {
  uint32_t u = __builtin_bit_cast(uint32_t, f);
  u += 0x7fffu + ((u >> 16) & 1u);   // round-to-nearest-even
  return (uint16_t)(u >> 16);
}

// async global->LDS, 16B per lane; LDS dest = wave-uniform base + lane*16
__device__ __forceinline__ void g2lds16(const uint16_t* g, uint16_t* l) {
  __builtin_amdgcn_global_load_lds((AS1 void*)g, (AS3 void*)l, 16, 0, 0);
}

// ---------------------------------------------------------------------------
// K0: cast A_stack (E,R,F)=(256,2048) -> bf16 flat; gather-transpose B_stack
// (E,O,R) -> Bb (O, K=E*R) K-major bf16.
// ---------------------------------------------------------------------------
__global__ __launch_bounds__(256) void prep_weights(
    const float* __restrict__ A, const float* __restrict__ Bst,
    uint16_t* __restrict__ Ab, uint16_t* __restrict__ Bb) {
  int idx = blockIdx.x * 256 + threadIdx.x;
  if (idx < KDIM * F_DIM) {
    Ab[idx] = f2bf(A[idx]);
  }
  if (idx < O_DIM * KDIM) {
    int k = idx & (KDIM - 1);
    int o = idx >> 8;
    int e = k >> 4, r = k & 15;
    Bb[idx] = f2bf(Bst[((size_t)e * O_DIM + o) * R_RANK + r]);
  }
}

// ---------------------------------------------------------------------------
// K1: fused x->bf16 conversion + routing sim + top-k + softmax(*scaling).
// Block 256 thr = 4 waves; wave owns 2 tokens; grid 1024 blocks (16 waves/CU).
// x -> registers directly; P chunk (16x256 fp32 = 16KB) staged in LDS.
// Per-lane fp32 chains (32 elems), cross-lane butterfly in double.
// ---------------------------------------------------------------------------
__global__ __launch_bounds__(256, 4) void route_convert(
    const float* __restrict__ x, const float* __restrict__ P,
    const float* __restrict__ scaling, const int* __restrict__ topk,
    uint16_t* __restrict__ xb, float* __restrict__ coeffS) {
  __shared__ float ps[16 * 256];

  const int tid  = threadIdx.x;
  const int lane = tid & 63;
  const int wid  = tid >> 6;
  const int t0   = blockIdx.x * 8 + wid * 2;
  const int er   = tid >> 4;           // 0..15 : P row for staging
  const int eq   = tid & 15;           // 0..15 : column group

  float acc0[16], acc1[16];
  #pragma unroll
  for (int e = 0; e < 16; ++e) { acc0[e] = 0.f; acc1[e] = 0.f; }

  const float* xr0 = x + (size_t)t0 * F_DIM;
  const float* xr1 = x + (size_t)(t0 + 1) * F_DIM;
  uint16_t* xw0 = xb + (size_t)t0 * F_DIM;
  uint16_t* xw1 = xb + (size_t)(t0 + 1) * F_DIM;

  for (int c = 0; c < 8; ++c) {
    const int f0 = c * 256;
    __syncthreads();   // protect previous chunk's LDS reads
    #pragma unroll
    for (int j = 0; j < 4; ++j) {
      const int col = eq * 4 + j * 64;  // lanes cover banks 2-way -> free
      *(float4*)&ps[er * 256 + col] =
          *(const float4*)&P[(size_t)er * F_DIM + f0 + col];
    }
    float4 xv0 = *(const float4*)&xr0[f0 + lane * 4];
    float4 xv1 = *(const float4*)&xr1[f0 + lane * 4];
    uint2 pk0, pk1;
    pk0.x = (uint32_t)f2bf(xv0.x) | ((uint32_t)f2bf(xv0.y) << 16);
    pk0.y = (uint32_t)f2bf(xv0.z) | ((uint32_t)f2bf(xv0.w) << 16);
    pk1.x = (uint32_t)f2bf(xv1.x) | ((uint32_t)f2bf(xv1.y) << 16);
    pk1.y = (uint32_t)f2bf(xv1.z) | ((uint32_t)f2bf(xv1.w) << 16);
    *(uint2*)&xw0[f0 + lane * 4] = pk0;
    *(uint2*)&xw1[f0 + lane * 4] = pk1;
    __syncthreads();
    #pragma unroll
    for (int e = 0; e < 16; ++e) {
      float4 pv = *(float4*)&ps[e * 256 + lane * 4];  // consecutive b128: conflict-free
      acc0[e] += xv0.x * pv.x; acc0[e] += xv0.y * pv.y;
      acc0[e] += xv0.z * pv.z; acc0[e] += xv0.w * pv.w;
      acc1[e] += xv1.x * pv.x; acc1[e] += xv1.y * pv.y;
      acc1[e] += xv1.z * pv.z; acc1[e] += xv1.w * pv.w;
    }
  }

  // cross-lane reduce in double (64 lanes each hold 32-elem fp32 partial)
  double s0[16], s1[16];
  #pragma unroll
  for (int e = 0; e < 16; ++e) {
    double d0 = (double)acc0[e];
    double d1 = (double)acc1[e];
    #pragma unroll
    for (int m = 1; m < 64; m <<= 1) {
      d0 += __shfl_xor(d0, m, 64);
      d1 += __shfl_xor(d1, m, 64);
    }
    s0[e] = fabs(d0);
    s1[e] = fabs(d1);
  }

  if (lane < 2) {
    double v[16];
    #pragma unroll
    for (int e = 0; e < 16; ++e) v[e] = lane ? s1[e] : s0[e];
    int k = topk[0];
    if (k > 16) k = 16;
    if (k < 1)  k = 1;
    unsigned mask = 0;
    double mx = 0.0;
    float ssum = 0.f;
    for (int i = 0; i < k; ++i) {
      double bv = -1.0; int bj = 0;
      #pragma unroll
      for (int j = 0; j < 16; ++j) {
        bool ok = !((mask >> j) & 1u) && (v[j] > bv);
        bv = ok ? v[j] : bv;
        bj = ok ? j  : bj;
      }
      mask |= 1u << bj;
      if (i == 0) mx = bv;
      ssum += expf((float)(bv - mx));
    }
    const float sc = scaling[0];
    float* cw = coeffS + (size_t)(t0 + lane) * 16;
    #pragma unroll
    for (int j = 0; j < 16; ++j) {
      float co = ((mask >> j) & 1u)
               ? expf((float)(v[j] - mx)) / ssum * sc : 0.f;
      cw[j] = co;
    }
  }
}

// ---------------------------------------------------------------------------
// Shared GEMM geometry: 64x64 block tile, BK=64, 4 waves 2x2, wave 32x32.
// Staging via global_load_lds (16B/lane) into unpadded [64 rows][8 granules]
// with XOR swizzle: LDS granule (r, gc) holds source granule gc ^ (r&7).
// Fragment b128 reads then spread 2-way across banks (free).
// ---------------------------------------------------------------------------
__global__ __launch_bounds__(256) void gemm_xa(
    const uint16_t* __restrict__ xb, const uint16_t* __restrict__ Ab,
    const float* __restrict__ coeffS, uint16_t* __restrict__ wb) {
  __shared__ uint16_t Xs[64 * 64];
  __shared__ uint16_t As[64 * 64];
  const int tid  = threadIdx.x;
  const int n0   = blockIdx.x * 64;
  const int m0   = blockIdx.y * 64;
  const int lane = tid & 63;
  const int wid  = tid >> 6;
  const int wm   = (wid >> 1) * 32;
  const int wn   = (wid & 1) * 32;
  const int quad = lane >> 4;
  const int cl   = lane & 15;

  // staging: wave stages granules [wid*64 + lane] and [+256]
  const int G0 = wid * 64 + lane;
  const int G1 = G0 + 256;
  const int r0 = G0 >> 3, g0 = (G0 & 7) ^ (r0 & 7);
  const int r1 = G1 >> 3, g1 = (G1 & 7) ^ (r1 & 7);
  const uint16_t* xsrc0 = xb + (size_t)(m0 + r0) * F_DIM + g0 * 8;
  const uint16_t* xsrc1 = xb + (size_t)(m0 + r1) * F_DIM + g1 * 8;
  const uint16_t* asrc0 = Ab + (size_t)(n0 + r0) * F_DIM + g0 * 8;
  const uint16_t* asrc1 = Ab + (size_t)(n0 + r1) * F_DIM + g1 * 8;
  uint16_t* xd0 = &Xs[(wid * 64) * 8];
  uint16_t* xd1 = &Xs[(wid * 64 + 256) * 8];
  uint16_t* ad0 = &As[(wid * 64) * 8];
  uint16_t* ad1 = &As[(wid * 64 + 256) * 8];

  const int ma0 = wm + cl, ma1 = wm + 16 + cl;
  const int nb0 = wn + cl, nb1 = wn + 16 + cl;

  v4f acc[2][2];
  #pragma unroll
  for (int i = 0; i < 2; i++)
    #pragma unroll
    for (int j = 0; j < 2; j++) acc[i][j] = (v4f){0.f, 0.f, 0.f, 0.f};

  for (int k0 = 0; k0 < F_DIM; k0 += 64) {
    __syncthreads();
    g2lds16(xsrc0 + k0, xd0);
    g2lds16(xsrc1 + k0, xd1);
    g2lds16(asrc0 + k0, ad0);
    g2lds16(asrc1 + k0, ad1);
    __syncthreads();
    #pragma unroll
    for (int ks = 0; ks < 2; ++ks) {
      const int gk = ks * 4 + quad;
      v8s a0 = *(v8s*)&Xs[(ma0 * 8 + (gk ^ (ma0 & 7))) * 8];
      v8s a1 = *(v8s*)&Xs[(ma1 * 8 + (gk ^ (ma1 & 7))) * 8];
      v8s b0 = *(v8s*)&As[(nb0 * 8 + (gk ^ (nb0 & 7))) * 8];
      v8s b1 = *(v8s*)&As[(nb1 * 8 + (gk ^ (nb1 & 7))) * 8];
      acc[0][0] = __builtin_amdgcn_mfma_f32_16x16x32_bf16(a0, b0, acc[0][0], 0, 0, 0);
      acc[0][1] = __builtin_amdgcn_mfma_f32_16x16x32_bf16(a0, b1, acc[0][1], 0, 0, 0);
      acc[1][0] = __builtin_amdgcn_mfma_f32_16x16x32_bf16(a1, b0, acc[1][0], 0, 0, 0);
      acc[1][1] = __builtin_amdgcn_mfma_f32_16x16x32_bf16(a1, b1, acc[1][1], 0, 0, 0);
    }
  }

  #pragma unroll
  for (int mi = 0; mi < 2; mi++)
    #pragma unroll
    for (int ni = 0; ni < 2; ni++) {
      const int n = n0 + wn + ni * 16 + cl;
      const int eidx = n >> 4;
      #pragma unroll
      for (int reg = 0; reg < 4; reg++) {
        const int t = m0 + wm + mi * 16 + quad * 4 + reg;
        float wv = acc[mi][ni][reg] * coeffS[(size_t)t * 16 + eidx];
        wb[(size_t)t * KDIM + n] = f2bf(wv);
      }
    }
}

__global__ __launch_bounds__(256) void gemm_wb(
    const uint16_t* __restrict__ wb, const uint16_t* __restrict__ Bb,
    float* __restrict__ out) {
  __shared__ uint16_t Ws[64 * 64];
  __shared__ uint16_t Bs[64 * 64];
  const int tid  = threadIdx.x;
  const int n0   = blockIdx.x * 64;
  const int m0   = blockIdx.y * 64;
  const int lane = tid & 63;
  const int wid  = tid >> 6;
  const int wm   = (wid >> 1) * 32;
  const int wn   = (wid & 1) * 32;
  const int quad = lane >> 4;
  const int cl   = lane & 15;

  const int G0 = wid * 64 + lane;
  const int G1 = G0 + 256;
  const int r0 = G0 >> 3, g0 = (G0 & 7) ^ (r0 & 7);
  const int r1 = G1 >> 3, g1 = (G1 & 7) ^ (r1 & 7);
  const uint16_t* wsrc0 = wb + (size_t)(m0 + r0) * KDIM + g0 * 8;
  const uint16_t* wsrc1 = wb + (size_t)(m0 + r1) * KDIM + g1 * 8;
  const uint16_t* bsrc0 = Bb + (size_t)(n0 + r0) * KDIM + g0 * 8;
  const uint16_t* bsrc1 = Bb + (size_t)(n0 + r1) * KDIM + g1 * 8;
  uint16_t* wd0 = &Ws[(wid * 64) * 8];
  uint16_t* wd1 = &Ws[(wid * 64 + 256) * 8];
  uint16_t* bd0 = &Bs[(wid * 64) * 8];
  uint16_t* bd1 = &Bs[(wid * 64 + 256) * 8];

  const int ma0 = wm + cl, ma1 = wm + 16 + cl;
  const int nb0 = wn + cl, nb1 = wn + 16 + cl;

  v4f acc[2][2];
  #pragma unroll
  for (int i = 0; i < 2; i++)
    #pragma unroll
    for (int j = 0; j < 2; j++) acc[i][j] = (v4f){0.f, 0.f, 0.f, 0.f};

  for (int k0 = 0; k0 < KDIM; k0 += 64) {
    __syncthreads();
    g2lds16(wsrc0 + k0, wd0);
    g2lds16(wsrc1 + k0, wd1);
    g2lds16(bsrc0 + k0, bd0);
    g2lds16(bsrc1 + k0, bd1);
    __syncthreads();
    #pragma unroll
    for (int ks = 0; ks < 2; ++ks) {
      const int gk = ks * 4 + quad;
      v8s a0 = *(v8s*)&Ws[(ma0 * 8 + (gk ^ (ma0 & 7))) * 8];
      v8s a1 = *(v8s*)&Ws[(ma1 * 8 + (gk ^ (ma1 & 7))) * 8];
      v8s b0 = *(v8s*)&Bs[(nb0 * 8 + (gk ^ (nb0 & 7))) * 8];
      v8s b1 = *(v8s*)&Bs[(nb1 * 8 + (gk ^ (nb1 & 7))) * 8];
      acc[0][0] = __builtin_amdgcn_mfma_f32_16x16x32_bf16(a0, b0, acc[0][0], 0, 0, 0);
      acc[0][1] = __builtin_amdgcn_mfma_f32_16x16x32_bf16(a0, b1, acc[0][1], 0, 0, 0);
      acc[1][0] = __builtin_amdgcn_mfma_f32_16x16x32_bf16(a1, b0, acc[1][0], 0, 0, 0);
      acc[1][1] = __builtin_amdgcn_mfma_f32_16x16x32_bf16(a1, b1, acc[1][1], 0, 0, 0);
    }
  }

  #pragma unroll
  for (int mi = 0; mi < 2; mi++)
    #pragma unroll
    for (int ni = 0; ni < 2; ni++) {
      const int o = n0 + wn + ni * 16 + cl;
      #pragma unroll
      for (int reg = 0; reg < 4; reg++) {
        const int t = m0 + wm + mi * 16 + quad * 4 + reg;
        out[(size_t)t * O_DIM + o] = acc[mi][ni][reg];
      }
    }
}

extern "C" void kernel_launch(void* const* d_in, const int* in_sizes, int n_in,
                              void* d_out, int out_size, void* d_ws, size_t ws_size,
                              hipStream_t stream) {
  (void)in_sizes; (void)n_in; (void)out_size; (void)ws_size;
  const float* x       = (const float*)d_in[0];
  const float* P       = (const float*)d_in[1];
  const float* A       = (const float*)d_in[2];
  const float* Bst     = (const float*)d_in[3];
  const float* scaling = (const float*)d_in[4];
  const int*   topk    = (const int*)d_in[5];
  float* out = (float*)d_out;

  char* ws = (char*)d_ws;
  uint16_t* xb     = (uint16_t*)(ws);                 // 33,554,432 B
  uint16_t* Ab     = (uint16_t*)(ws + 33554432);      //  1,048,576 B
  uint16_t* Bb     = (uint16_t*)(ws + 34603008);      //  1,048,576 B
  uint16_t* wbuf   = (uint16_t*)(ws + 35651584);      //  4,194,304 B
  float*    coeffS = (float*)   (ws + 39845888);      //    524,288 B

  hipLaunchKernelGGL(prep_weights, dim3(2048), dim3(256), 0, stream, A, Bst, Ab, Bb);
  hipLaunchKernelGGL(route_convert, dim3(T_TOKENS / 8), dim3(256), 0, stream,
                     x, P, scaling, topk, xb, coeffS);
  hipLaunchKernelGGL(gemm_xa, dim3(KDIM / 64, T_TOKENS / 64), dim3(256), 0, stream,
                     xb, Ab, coeffS, wbuf);
  hipLaunchKernelGGL(gemm_wb, dim3(O_DIM / 64, T_TOKENS / 64), dim3(256), 0, stream,
                     wbuf, Bb, out);
}

// Round 3
// 189.340 us; speedup vs baseline: 1.4113x; 1.0742x over previous
//
#include <hip/hip_runtime.h>
#include <hip/hip_bf16.h>
#include <stdint.h>

#define T_TOKENS 8192
#define F_DIM    2048
#define E_EXP    16
#define R_RANK   16
#define O_DIM    2048
#define KDIM     (E_EXP * R_RANK)   // 256

typedef short v8s __attribute__((ext_vector_type(8)));
typedef float v4f __attribute__((ext_vector_type(4)));

#define AS1 __attribute__((address_space(1)))
#define AS3 __attribute__((address_space(3)))

__device__ __forceinline__ uint16_t f2bf(float f) {
  uint32_t u = __builtin_bit_cast(uint32_t, f);
  u += 0x7fffu + ((u >> 16) & 1u);   // round-to-nearest-even
  return (uint16_t)(u >> 16);
}

// async global->LDS, 16B per lane; LDS dest = wave-uniform base + lane*16
__device__ __forceinline__ void g2lds16(const uint16_t* g, uint16_t* l) {
  __builtin_amdgcn_global_load_lds((AS1 void*)g, (AS3 void*)l, 16, 0, 0);
}

// ---------------------------------------------------------------------------
// K0: cast A_stack -> bf16; gather-transpose B_stack (E,O,R) -> Bb (O,K) bf16.
// ---------------------------------------------------------------------------
__global__ __launch_bounds__(256) void prep_weights(
    const float* __restrict__ A, const float* __restrict__ Bst,
    uint16_t* __restrict__ Ab, uint16_t* __restrict__ Bb) {
  int idx = blockIdx.x * 256 + threadIdx.x;
  if (idx < KDIM * F_DIM) {
    Ab[idx] = f2bf(A[idx]);
  }
  if (idx < O_DIM * KDIM) {
    int k = idx & (KDIM - 1);
    int o = idx >> 8;
    int e = k >> 4, r = k & 15;
    Bb[idx] = f2bf(Bst[((size_t)e * O_DIM + o) * R_RANK + r]);
  }
}

// ---------------------------------------------------------------------------
// K1a: streaming x->bf16 + partial sims.
// grid (chunk c=0..7, token-block by=0..127), 256 thr.
// One P-chunk LDS stage + one barrier, then barrier-free streaming.
// Thread: 16 lanes per 4-token group; 4-token register blocking (64 fp32 acc).
// Partials layout: float4 partials4[(c*4+e4)*8192 + t]  (coalesced R+W).
// ---------------------------------------------------------------------------
__global__ __launch_bounds__(256) void route_stream(
    const float* __restrict__ x, const float* __restrict__ P,
    uint16_t* __restrict__ xb, float4* __restrict__ partials4) {
  __shared__ float ps[16 * 260];
  const int tid = threadIdx.x;
  const int c   = blockIdx.x;
  const int by  = blockIdx.y;
  const int f0  = c * 256;

  {
    const int e = tid >> 4;
    #pragma unroll
    for (int j = 0; j < 4; ++j) {
      const int col = (tid & 15) * 4 + j * 64;
      *(float4*)&ps[e * 260 + col] =
          *(const float4*)&P[(size_t)e * F_DIM + f0 + col];
    }
  }
  __syncthreads();

  const int sub = tid & 15;
  const int tg  = tid >> 4;
  const int t0  = by * 64 + tg * 4;
  const float* xr = x + (size_t)t0 * F_DIM + f0;
  uint16_t*    xw = xb + (size_t)t0 * F_DIM + f0;

  float a0[16], a1[16], a2[16], a3[16];
  #pragma unroll
  for (int e = 0; e < 16; ++e) { a0[e] = 0.f; a1[e] = 0.f; a2[e] = 0.f; a3[e] = 0.f; }

  #pragma unroll
  for (int j = 0; j < 4; ++j) {
    const int off = sub * 4 + j * 64;
    float4 v0 = *(const float4*)&xr[off];
    float4 v1 = *(const float4*)&xr[F_DIM + off];
    float4 v2 = *(const float4*)&xr[2 * F_DIM + off];
    float4 v3 = *(const float4*)&xr[3 * F_DIM + off];
    uint2 p0, p1, p2, p3;
    p0.x = (uint32_t)f2bf(v0.x) | ((uint32_t)f2bf(v0.y) << 16);
    p0.y = (uint32_t)f2bf(v0.z) | ((uint32_t)f2bf(v0.w) << 16);
    p1.x = (uint32_t)f2bf(v1.x) | ((uint32_t)f2bf(v1.y) << 16);
    p1.y = (uint32_t)f2bf(v1.z) | ((uint32_t)f2bf(v1.w) << 16);
    p2.x = (uint32_t)f2bf(v2.x) | ((uint32_t)f2bf(v2.y) << 16);
    p2.y = (uint32_t)f2bf(v2.z) | ((uint32_t)f2bf(v2.w) << 16);
    p3.x = (uint32_t)f2bf(v3.x) | ((uint32_t)f2bf(v3.y) << 16);
    p3.y = (uint32_t)f2bf(v3.z) | ((uint32_t)f2bf(v3.w) << 16);
    *(uint2*)&xw[off]             = p0;
    *(uint2*)&xw[F_DIM + off]     = p1;
    *(uint2*)&xw[2 * F_DIM + off] = p2;
    *(uint2*)&xw[3 * F_DIM + off] = p3;
    #pragma unroll
    for (int e = 0; e < 16; ++e) {
      float4 pv = *(float4*)&ps[e * 260 + off];
      a0[e] += v0.x * pv.x; a0[e] += v0.y * pv.y; a0[e] += v0.z * pv.z; a0[e] += v0.w * pv.w;
      a1[e] += v1.x * pv.x; a1[e] += v1.y * pv.y; a1[e] += v1.z * pv.z; a1[e] += v1.w * pv.w;
      a2[e] += v2.x * pv.x; a2[e] += v2.y * pv.y; a2[e] += v2.z * pv.z; a2[e] += v2.w * pv.w;
      a3[e] += v3.x * pv.x; a3[e] += v3.y * pv.y; a3[e] += v3.z * pv.z; a3[e] += v3.w * pv.w;
    }
  }

  // reduce across the 16 lanes of each token group (fp32 tree)
  #pragma unroll
  for (int e = 0; e < 16; ++e) {
    #pragma unroll
    for (int m = 1; m < 16; m <<= 1) {
      a0[e] += __shfl_xor(a0[e], m, 64);
      a1[e] += __shfl_xor(a1[e], m, 64);
      a2[e] += __shfl_xor(a2[e], m, 64);
      a3[e] += __shfl_xor(a3[e], m, 64);
    }
  }

  const size_t cb = (size_t)c * 4;
  if (sub == 0) {
    #pragma unroll
    for (int e4 = 0; e4 < 4; ++e4)
      partials4[(cb + e4) * T_TOKENS + t0] =
          make_float4(a0[e4 * 4], a0[e4 * 4 + 1], a0[e4 * 4 + 2], a0[e4 * 4 + 3]);
  } else if (sub == 1) {
    #pragma unroll
    for (int e4 = 0; e4 < 4; ++e4)
      partials4[(cb + e4) * T_TOKENS + t0 + 1] =
          make_float4(a1[e4 * 4], a1[e4 * 4 + 1], a1[e4 * 4 + 2], a1[e4 * 4 + 3]);
  } else if (sub == 2) {
    #pragma unroll
    for (int e4 = 0; e4 < 4; ++e4)
      partials4[(cb + e4) * T_TOKENS + t0 + 2] =
          make_float4(a2[e4 * 4], a2[e4 * 4 + 1], a2[e4 * 4 + 2], a2[e4 * 4 + 3]);
  } else if (sub == 3) {
    #pragma unroll
    for (int e4 = 0; e4 < 4; ++e4)
      partials4[(cb + e4) * T_TOKENS + t0 + 3] =
          make_float4(a3[e4 * 4], a3[e4 * 4 + 1], a3[e4 * 4 + 2], a3[e4 * 4 + 3]);
  }
}

// ---------------------------------------------------------------------------
// K1b: per-token fp64 cross-chunk sum + |.| + top-k + softmax(*scaling).
// ---------------------------------------------------------------------------
__global__ __launch_bounds__(256) void route_topk(
    const float4* __restrict__ partials4, const float* __restrict__ scaling,
    const int* __restrict__ topk, float* __restrict__ coeffS) {
  const int t = blockIdx.x * 256 + threadIdx.x;
  double s[16];
  #pragma unroll
  for (int e = 0; e < 16; ++e) s[e] = 0.0;
  for (int c = 0; c < 8; ++c) {
    #pragma unroll
    for (int e4 = 0; e4 < 4; ++e4) {
      float4 p = partials4[((size_t)c * 4 + e4) * T_TOKENS + t];
      s[e4 * 4]     += (double)p.x;
      s[e4 * 4 + 1] += (double)p.y;
      s[e4 * 4 + 2] += (double)p.z;
      s[e4 * 4 + 3] += (double)p.w;
    }
  }
  double v[16];
  #pragma unroll
  for (int e = 0; e < 16; ++e) v[e] = fabs(s[e]);

  int k = topk[0];
  if (k > 16) k = 16;
  if (k < 1)  k = 1;
  unsigned mask = 0;
  double mx = 0.0;
  float ssum = 0.f;
  for (int i = 0; i < k; ++i) {
    double bv = -1.0; int bj = 0;
    #pragma unroll
    for (int j = 0; j < 16; ++j) {
      bool ok = !((mask >> j) & 1u) && (v[j] > bv);
      bv = ok ? v[j] : bv;
      bj = ok ? j  : bj;
    }
    mask |= 1u << bj;
    if (i == 0) mx = bv;
    ssum += expf((float)(bv - mx));
  }
  const float sc = scaling[0];
  float co[16];
  #pragma unroll
  for (int j = 0; j < 16; ++j)
    co[j] = ((mask >> j) & 1u) ? expf((float)(v[j] - mx)) / ssum * sc : 0.f;
  float* cw = coeffS + (size_t)t * 16;
  #pragma unroll
  for (int j4 = 0; j4 < 4; ++j4)
    *(float4*)&cw[j4 * 4] = make_float4(co[j4 * 4], co[j4 * 4 + 1],
                                        co[j4 * 4 + 2], co[j4 * 4 + 3]);
}

// ---------------------------------------------------------------------------
// GEMM common geometry: 64x64 tile, BK=128 as two 64-col sub-buffers, 4 waves
// 2x2, wave 32x32 (2x2 MFMA). Staging global_load_lds 16B/lane, XOR-swizzled
// unpadded layout (slot (r,s) holds source granule s ^ (r&7)). LDS-bounce
// vectorized epilogues.
// ---------------------------------------------------------------------------
__global__ __launch_bounds__(256) void gemm_xa(
    const uint16_t* __restrict__ xb, const uint16_t* __restrict__ Ab,
    const float* __restrict__ coeffS, uint16_t* __restrict__ wb) {
  __shared__ uint16_t S[16384];   // 32 KB
  uint16_t* Xh[2] = { S,         S + 4096  };
  uint16_t* Ah[2] = { S + 8192,  S + 12288 };
  const int tid  = threadIdx.x;
  const int n0   = blockIdx.x * 64;
  const int m0   = blockIdx.y * 64;
  const int lane = tid & 63;
  const int wid  = tid >> 6;
  const int wm   = (wid >> 1) * 32;
  const int wn   = (wid & 1) * 32;
  const int quad = lane >> 4;
  const int cl   = lane & 15;

  const int G0 = wid * 64 + lane;
  const int G1 = G0 + 256;
  const int r0 = G0 >> 3, g0 = (G0 & 7) ^ (r0 & 7);
  const int r1 = G1 >> 3, g1 = (G1 & 7) ^ (r1 & 7);
  const uint16_t* xs0 = xb + (size_t)(m0 + r0) * F_DIM + g0 * 8;
  const uint16_t* xs1 = xb + (size_t)(m0 + r1) * F_DIM + g1 * 8;
  const uint16_t* as0 = Ab + (size_t)(n0 + r0) * F_DIM + g0 * 8;
  const uint16_t* as1 = Ab + (size_t)(n0 + r1) * F_DIM + g1 * 8;
  const int d0 = wid * 512;
  const int d1 = wid * 512 + 2048;

  const int ma0 = wm + cl, ma1 = wm + 16 + cl;
  const int nb0 = wn + cl, nb1 = wn + 16 + cl;

  v4f acc[2][2];
  #pragma unroll
  for (int i = 0; i < 2; i++)
    #pragma unroll
    for (int j = 0; j < 2; j++) acc[i][j] = (v4f){0.f, 0.f, 0.f, 0.f};

  for (int k0 = 0; k0 < F_DIM; k0 += 128) {
    __syncthreads();
    g2lds16(xs0 + k0,      Xh[0] + d0);
    g2lds16(xs1 + k0,      Xh[0] + d1);
    g2lds16(as0 + k0,      Ah[0] + d0);
    g2lds16(as1 + k0,      Ah[0] + d1);
    g2lds16(xs0 + k0 + 64, Xh[1] + d0);
    g2lds16(xs1 + k0 + 64, Xh[1] + d1);
    g2lds16(as0 + k0 + 64, Ah[1] + d0);
    g2lds16(as1 + k0 + 64, Ah[1] + d1);
    __syncthreads();
    #pragma unroll
    for (int h = 0; h < 2; ++h) {
      #pragma unroll
      for (int ks = 0; ks < 2; ++ks) {
        const int gk = ks * 4 + quad;
        v8s fa0 = *(v8s*)&Xh[h][(ma0 * 8 + (gk ^ (ma0 & 7))) * 8];
        v8s fa1 = *(v8s*)&Xh[h][(ma1 * 8 + (gk ^ (ma1 & 7))) * 8];
        v8s fb0 = *(v8s*)&Ah[h][(nb0 * 8 + (gk ^ (nb0 & 7))) * 8];
        v8s fb1 = *(v8s*)&Ah[h][(nb1 * 8 + (gk ^ (nb1 & 7))) * 8];
        acc[0][0] = __builtin_amdgcn_mfma_f32_16x16x32_bf16(fa0, fb0, acc[0][0], 0, 0, 0);
        acc[0][1] = __builtin_amdgcn_mfma_f32_16x16x32_bf16(fa0, fb1, acc[0][1], 0, 0, 0);
        acc[1][0] = __builtin_amdgcn_mfma_f32_16x16x32_bf16(fa1, fb0, acc[1][0], 0, 0, 0);
        acc[1][1] = __builtin_amdgcn_mfma_f32_16x16x32_bf16(fa1, fb1, acc[1][1], 0, 0, 0);
      }
    }
  }

  // epilogue: coeff fold + bf16 pack via LDS bounce, 128B-contiguous stores
  __syncthreads();
  uint16_t* tile = S;   // stride 72
  #pragma unroll
  for (int mi = 0; mi < 2; mi++)
    #pragma unroll
    for (int ni = 0; ni < 2; ni++) {
      const int nl = wn + ni * 16 + cl;
      const int eidx = (n0 + nl) >> 4;
      #pragma unroll
      for (int reg = 0; reg < 4; reg++) {
        const int tl = wm + mi * 16 + quad * 4 + reg;
        float wv = acc[mi][ni][reg] * coeffS[(size_t)(m0 + tl) * 16 + eidx];
        tile[tl * 72 + nl] = f2bf(wv);
      }
    }
  __syncthreads();
  #pragma unroll
  for (int p = 0; p < 2; ++p) {
    const int row  = p * 32 + (tid >> 3);
    const int colg = (tid & 7) * 8;
    uint4 val = *(uint4*)&tile[row * 72 + colg];
    *(uint4*)&wb[(size_t)(m0 + row) * KDIM + n0 + colg] = val;
  }
}

__global__ __launch_bounds__(256) void gemm_wb(
    const uint16_t* __restrict__ wb, const uint16_t* __restrict__ Bb,
    float* __restrict__ out) {
  __shared__ uint16_t S[16384];   // 32 KB
  uint16_t* Wh[2] = { S,         S + 4096  };
  uint16_t* Bh[2] = { S + 8192,  S + 12288 };
  const int tid  = threadIdx.x;
  const int n0   = blockIdx.x * 64;
  const int m0   = blockIdx.y * 64;
  const int lane = tid & 63;
  const int wid  = tid >> 6;
  const int wm   = (wid >> 1) * 32;
  const int wn   = (wid & 1) * 32;
  const int quad = lane >> 4;
  const int cl   = lane & 15;

  const int G0 = wid * 64 + lane;
  const int G1 = G0 + 256;
  const int r0 = G0 >> 3, g0 = (G0 & 7) ^ (r0 & 7);
  const int r1 = G1 >> 3, g1 = (G1 & 7) ^ (r1 & 7);
  const uint16_t* ws0 = wb + (size_t)(m0 + r0) * KDIM + g0 * 8;
  const uint16_t* ws1 = wb + (size_t)(m0 + r1) * KDIM + g1 * 8;
  const uint16_t* bs0 = Bb + (size_t)(n0 + r0) * KDIM + g0 * 8;
  const uint16_t* bs1 = Bb + (size_t)(n0 + r1) * KDIM + g1 * 8;
  const int d0 = wid * 512;
  const int d1 = wid * 512 + 2048;

  const int ma0 = wm + cl, ma1 = wm + 16 + cl;
  const int nb0 = wn + cl, nb1 = wn + 16 + cl;

  v4f acc[2][2];
  #pragma unroll
  for (int i = 0; i < 2; i++)
    #pragma unroll
    for (int j = 0; j < 2; j++) acc[i][j] = (v4f){0.f, 0.f, 0.f, 0.f};

  #pragma unroll
  for (int k0 = 0; k0 < KDIM; k0 += 128) {
    __syncthreads();
    g2lds16(ws0 + k0,      Wh[0] + d0);
    g2lds16(ws1 + k0,      Wh[0] + d1);
    g2lds16(bs0 + k0,      Bh[0] + d0);
    g2lds16(bs1 + k0,      Bh[0] + d1);
    g2lds16(ws0 + k0 + 64, Wh[1] + d0);
    g2lds16(ws1 + k0 + 64, Wh[1] + d1);
    g2lds16(bs0 + k0 + 64, Bh[1] + d0);
    g2lds16(bs1 + k0 + 64, Bh[1] + d1);
    __syncthreads();
    #pragma unroll
    for (int h = 0; h < 2; ++h) {
      #pragma unroll
      for (int ks = 0; ks < 2; ++ks) {
        const int gk = ks * 4 + quad;
        v8s fa0 = *(v8s*)&Wh[h][(ma0 * 8 + (gk ^ (ma0 & 7))) * 8];
        v8s fa1 = *(v8s*)&Wh[h][(ma1 * 8 + (gk ^ (ma1 & 7))) * 8];
        v8s fb0 = *(v8s*)&Bh[h][(nb0 * 8 + (gk ^ (nb0 & 7))) * 8];
        v8s fb1 = *(v8s*)&Bh[h][(nb1 * 8 + (gk ^ (nb1 & 7))) * 8];
        acc[0][0] = __builtin_amdgcn_mfma_f32_16x16x32_bf16(fa0, fb0, acc[0][0], 0, 0, 0);
        acc[0][1] = __builtin_amdgcn_mfma_f32_16x16x32_bf16(fa0, fb1, acc[0][1], 0, 0, 0);
        acc[1][0] = __builtin_amdgcn_mfma_f32_16x16x32_bf16(fa1, fb0, acc[1][0], 0, 0, 0);
        acc[1][1] = __builtin_amdgcn_mfma_f32_16x16x32_bf16(fa1, fb1, acc[1][1], 0, 0, 0);
      }
    }
  }

  // epilogue: fp32 LDS bounce -> 256B-contiguous float4 stores
  __syncthreads();
  float* ft = (float*)S;   // stride 68 floats; 64*68*4 = 17408 B <= 32 KB
  #pragma unroll
  for (int mi = 0; mi < 2; mi++)
    #pragma unroll
    for (int ni = 0; ni < 2; ni++) {
      const int nl = wn + ni * 16 + cl;
      #pragma unroll
      for (int reg = 0; reg < 4; reg++) {
        const int tl = wm + mi * 16 + quad * 4 + reg;
        ft[tl * 68 + nl] = acc[mi][ni][reg];
      }
    }
  __syncthreads();
  #pragma unroll
  for (int p = 0; p < 4; ++p) {
    const int row = p * 16 + (tid >> 4);
    const int col = (tid & 15) * 4;
    float4 val = *(float4*)&ft[row * 68 + col];
    *(float4*)&out[(size_t)(m0 + row) * O_DIM + n0 + col] = val;
  }
}

extern "C" void kernel_launch(void* const* d_in, const int* in_sizes, int n_in,
                              void* d_out, int out_size, void* d_ws, size_t ws_size,
                              hipStream_t stream) {
  (void)in_sizes; (void)n_in; (void)out_size; (void)ws_size;
  const float* x       = (const float*)d_in[0];
  const float* P       = (const float*)d_in[1];
  const float* A       = (const float*)d_in[2];
  const float* Bst     = (const float*)d_in[3];
  const float* scaling = (const float*)d_in[4];
  const int*   topk    = (const int*)d_in[5];
  float* out = (float*)d_out;

  char* ws = (char*)d_ws;
  uint16_t* xb     = (uint16_t*)(ws);                 // 33,554,432 B
  uint16_t* Ab     = (uint16_t*)(ws + 33554432);      //  1,048,576 B
  uint16_t* Bb     = (uint16_t*)(ws + 34603008);      //  1,048,576 B
  // partials (4 MB) aliases wbuf: route_topk reads partials BEFORE gemm_xa
  // writes wbuf (stream-ordered), so reuse is safe.
  float4*   parts  = (float4*)  (ws + 35651584);      //  4,194,304 B
  uint16_t* wbuf   = (uint16_t*)(ws + 35651584);      //  4,194,304 B
  float*    coeffS = (float*)   (ws + 39845888);      //    524,288 B

  hipLaunchKernelGGL(prep_weights, dim3(2048), dim3(256), 0, stream, A, Bst, Ab, Bb);
  hipLaunchKernelGGL(route_stream, dim3(8, 128), dim3(256), 0, stream, x, P, xb, parts);
  hipLaunchKernelGGL(route_topk, dim3(T_TOKENS / 256), dim3(256), 0, stream,
                     parts, scaling, topk, coeffS);
  hipLaunchKernelGGL(gemm_xa, dim3(KDIM / 64, T_TOKENS / 64), dim3(256), 0, stream,
                     xb, Ab, coeffS, wbuf);
  hipLaunchKernelGGL(gemm_wb, dim3(O_DIM / 64, T_TOKENS / 64), dim3(256), 0, stream,
                     wbuf, Bb, out);
}

// Round 4
// 167.656 us; speedup vs baseline: 1.5939x; 1.1293x over previous
//
#include <hip/hip_runtime.h>
#include <hip/hip_bf16.h>
#include <stdint.h>

#define T_TOKENS 8192
#define F_DIM    2048
#define E_EXP    16
#define R_RANK   16
#define O_DIM    2048
#define KDIM     (E_EXP * R_RANK)   // 256

typedef short v8s __attribute__((ext_vector_type(8)));
typedef float v4f __attribute__((ext_vector_type(4)));

#define AS1 __attribute__((address_space(1)))
#define AS3 __attribute__((address_space(3)))

__device__ __forceinline__ uint16_t f2bf(float f) {
  uint32_t u = __builtin_bit_cast(uint32_t, f);
  u += 0x7fffu + ((u >> 16) & 1u);   // round-to-nearest-even
  return (uint16_t)(u >> 16);
}

// async global->LDS, 16B per lane; LDS dest = wave-uniform base + lane*16
__device__ __forceinline__ void g2lds16(const uint16_t* g, uint16_t* l) {
  __builtin_amdgcn_global_load_lds((AS1 void*)g, (AS3 void*)l, 16, 0, 0);
}

// ---------------------------------------------------------------------------
// K0: cast A_stack -> bf16; gather-transpose B_stack (E,O,R) -> Bb (O,K) bf16.
// ---------------------------------------------------------------------------
__global__ __launch_bounds__(256) void prep_weights(
    const float* __restrict__ A, const float* __restrict__ Bst,
    uint16_t* __restrict__ Ab, uint16_t* __restrict__ Bb) {
  int idx = blockIdx.x * 256 + threadIdx.x;
  if (idx < KDIM * F_DIM) {
    Ab[idx] = f2bf(A[idx]);
  }
  if (idx < O_DIM * KDIM) {
    int k = idx & (KDIM - 1);
    int o = idx >> 8;
    int e = k >> 4, r = k & 15;
    Bb[idx] = f2bf(Bst[((size_t)e * O_DIM + o) * R_RANK + r]);
  }
}

// ---------------------------------------------------------------------------
// K1: streaming x->bf16 + partial sims (chunked; fp32 16-elem lane chains).
// Partials layout: float4 partials4[(c*4+e4)*8192 + t]  (coalesced R+W).
// ---------------------------------------------------------------------------
__global__ __launch_bounds__(256) void route_stream(
    const float* __restrict__ x, const float* __restrict__ P,
    uint16_t* __restrict__ xb, float4* __restrict__ partials4) {
  __shared__ float ps[16 * 260];
  const int tid = threadIdx.x;
  const int c   = blockIdx.x;
  const int by  = blockIdx.y;
  const int f0  = c * 256;

  {
    const int e = tid >> 4;
    #pragma unroll
    for (int j = 0; j < 4; ++j) {
      const int col = (tid & 15) * 4 + j * 64;
      *(float4*)&ps[e * 260 + col] =
          *(const float4*)&P[(size_t)e * F_DIM + f0 + col];
    }
  }
  __syncthreads();

  const int sub = tid & 15;
  const int tg  = tid >> 4;
  const int t0  = by * 64 + tg * 4;
  const float* xr = x + (size_t)t0 * F_DIM + f0;
  uint16_t*    xw = xb + (size_t)t0 * F_DIM + f0;

  float a0[16], a1[16], a2[16], a3[16];
  #pragma unroll
  for (int e = 0; e < 16; ++e) { a0[e] = 0.f; a1[e] = 0.f; a2[e] = 0.f; a3[e] = 0.f; }

  #pragma unroll
  for (int j = 0; j < 4; ++j) {
    const int off = sub * 4 + j * 64;
    float4 v0 = *(const float4*)&xr[off];
    float4 v1 = *(const float4*)&xr[F_DIM + off];
    float4 v2 = *(const float4*)&xr[2 * F_DIM + off];
    float4 v3 = *(const float4*)&xr[3 * F_DIM + off];
    uint2 p0, p1, p2, p3;
    p0.x = (uint32_t)f2bf(v0.x) | ((uint32_t)f2bf(v0.y) << 16);
    p0.y = (uint32_t)f2bf(v0.z) | ((uint32_t)f2bf(v0.w) << 16);
    p1.x = (uint32_t)f2bf(v1.x) | ((uint32_t)f2bf(v1.y) << 16);
    p1.y = (uint32_t)f2bf(v1.z) | ((uint32_t)f2bf(v1.w) << 16);
    p2.x = (uint32_t)f2bf(v2.x) | ((uint32_t)f2bf(v2.y) << 16);
    p2.y = (uint32_t)f2bf(v2.z) | ((uint32_t)f2bf(v2.w) << 16);
    p3.x = (uint32_t)f2bf(v3.x) | ((uint32_t)f2bf(v3.y) << 16);
    p3.y = (uint32_t)f2bf(v3.z) | ((uint32_t)f2bf(v3.w) << 16);
    *(uint2*)&xw[off]             = p0;
    *(uint2*)&xw[F_DIM + off]     = p1;
    *(uint2*)&xw[2 * F_DIM + off] = p2;
    *(uint2*)&xw[3 * F_DIM + off] = p3;
    #pragma unroll
    for (int e = 0; e < 16; ++e) {
      float4 pv = *(float4*)&ps[e * 260 + off];
      a0[e] += v0.x * pv.x; a0[e] += v0.y * pv.y; a0[e] += v0.z * pv.z; a0[e] += v0.w * pv.w;
      a1[e] += v1.x * pv.x; a1[e] += v1.y * pv.y; a1[e] += v1.z * pv.z; a1[e] += v1.w * pv.w;
      a2[e] += v2.x * pv.x; a2[e] += v2.y * pv.y; a2[e] += v2.z * pv.z; a2[e] += v2.w * pv.w;
      a3[e] += v3.x * pv.x; a3[e] += v3.y * pv.y; a3[e] += v3.z * pv.z; a3[e] += v3.w * pv.w;
    }
  }

  #pragma unroll
  for (int e = 0; e < 16; ++e) {
    #pragma unroll
    for (int m = 1; m < 16; m <<= 1) {
      a0[e] += __shfl_xor(a0[e], m, 64);
      a1[e] += __shfl_xor(a1[e], m, 64);
      a2[e] += __shfl_xor(a2[e], m, 64);
      a3[e] += __shfl_xor(a3[e], m, 64);
    }
  }

  const size_t cb = (size_t)c * 4;
  if (sub == 0) {
    #pragma unroll
    for (int e4 = 0; e4 < 4; ++e4)
      partials4[(cb + e4) * T_TOKENS + t0] =
          make_float4(a0[e4 * 4], a0[e4 * 4 + 1], a0[e4 * 4 + 2], a0[e4 * 4 + 3]);
  } else if (sub == 1) {
    #pragma unroll
    for (int e4 = 0; e4 < 4; ++e4)
      partials4[(cb + e4) * T_TOKENS + t0 + 1] =
          make_float4(a1[e4 * 4], a1[e4 * 4 + 1], a1[e4 * 4 + 2], a1[e4 * 4 + 3]);
  } else if (sub == 2) {
    #pragma unroll
    for (int e4 = 0; e4 < 4; ++e4)
      partials4[(cb + e4) * T_TOKENS + t0 + 2] =
          make_float4(a2[e4 * 4], a2[e4 * 4 + 1], a2[e4 * 4 + 2], a2[e4 * 4 + 3]);
  } else if (sub == 3) {
    #pragma unroll
    for (int e4 = 0; e4 < 4; ++e4)
      partials4[(cb + e4) * T_TOKENS + t0 + 3] =
          make_float4(a3[e4 * 4], a3[e4 * 4 + 1], a3[e4 * 4 + 2], a3[e4 * 4 + 3]);
  }
}

// ---------------------------------------------------------------------------
// K2: gemm_xa, 64x64 tile BK=128, XCD-swizzled linear grid, topk folded into
// prologue (tid<64: fp64 cross-chunk sum + topk + softmax -> coeffL).
// ---------------------------------------------------------------------------
__global__ __launch_bounds__(256) void gemm_xa(
    const uint16_t* __restrict__ xb, const uint16_t* __restrict__ Ab,
    const float4* __restrict__ partials4, const float* __restrict__ scaling,
    const int* __restrict__ topk, uint16_t* __restrict__ wb) {
  __shared__ uint16_t S[16384];   // 32 KB staging
  __shared__ float coeffL[64 * 17];
  uint16_t* Xh[2] = { S,         S + 4096  };
  uint16_t* Ah[2] = { S + 8192,  S + 12288 };
  const int tid  = threadIdx.x;
  const int b    = blockIdx.x;                       // 512 blocks
  const int m_idx = (b & 7) + ((b >> 5) << 3);       // 0..127 (same-XCD share m)
  const int n_idx = (b >> 3) & 3;                    // 0..3
  const int m0 = m_idx * 64, n0 = n_idx * 64;
  const int lane = tid & 63;
  const int wid  = tid >> 6;
  const int wm   = (wid >> 1) * 32;
  const int wn   = (wid & 1) * 32;
  const int quad = lane >> 4;
  const int cl   = lane & 15;

  // ---- routing prologue: tokens m0..m0+63 ----
  if (tid < 64) {
    const int t = m0 + tid;
    double s[16];
    #pragma unroll
    for (int e = 0; e < 16; ++e) s[e] = 0.0;
    for (int c = 0; c < 8; ++c) {
      #pragma unroll
      for (int e4 = 0; e4 < 4; ++e4) {
        float4 p = partials4[((size_t)c * 4 + e4) * T_TOKENS + t];
        s[e4 * 4]     += (double)p.x;
        s[e4 * 4 + 1] += (double)p.y;
        s[e4 * 4 + 2] += (double)p.z;
        s[e4 * 4 + 3] += (double)p.w;
      }
    }
    double v[16];
    #pragma unroll
    for (int e = 0; e < 16; ++e) v[e] = fabs(s[e]);
    int k = topk[0];
    if (k > 16) k = 16;
    if (k < 1)  k = 1;
    unsigned mask = 0;
    double mx = 0.0;
    float ssum = 0.f;
    for (int i = 0; i < k; ++i) {
      double bv = -1.0; int bj = 0;
      #pragma unroll
      for (int j = 0; j < 16; ++j) {
        bool ok = !((mask >> j) & 1u) && (v[j] > bv);
        bv = ok ? v[j] : bv;
        bj = ok ? j  : bj;
      }
      mask |= 1u << bj;
      if (i == 0) mx = bv;
      ssum += expf((float)(bv - mx));
    }
    const float sc = scaling[0];
    #pragma unroll
    for (int j = 0; j < 16; ++j)
      coeffL[tid * 17 + j] = ((mask >> j) & 1u)
          ? expf((float)(v[j] - mx)) / ssum * sc : 0.f;
  }

  // ---- GEMM ----
  const int G0 = wid * 64 + lane;
  const int G1 = G0 + 256;
  const int r0 = G0 >> 3, g0 = (G0 & 7) ^ (r0 & 7);
  const int r1 = G1 >> 3, g1 = (G1 & 7) ^ (r1 & 7);
  const uint16_t* xs0 = xb + (size_t)(m0 + r0) * F_DIM + g0 * 8;
  const uint16_t* xs1 = xb + (size_t)(m0 + r1) * F_DIM + g1 * 8;
  const uint16_t* as0 = Ab + (size_t)(n0 + r0) * F_DIM + g0 * 8;
  const uint16_t* as1 = Ab + (size_t)(n0 + r1) * F_DIM + g1 * 8;
  const int d0 = wid * 512;
  const int d1 = wid * 512 + 2048;

  const int ma0 = wm + cl, ma1 = wm + 16 + cl;
  const int nb0 = wn + cl, nb1 = wn + 16 + cl;

  v4f acc[2][2];
  #pragma unroll
  for (int i = 0; i < 2; i++)
    #pragma unroll
    for (int j = 0; j < 2; j++) acc[i][j] = (v4f){0.f, 0.f, 0.f, 0.f};

  for (int k0 = 0; k0 < F_DIM; k0 += 128) {
    __syncthreads();
    g2lds16(xs0 + k0,      Xh[0] + d0);
    g2lds16(xs1 + k0,      Xh[0] + d1);
    g2lds16(as0 + k0,      Ah[0] + d0);
    g2lds16(as1 + k0,      Ah[0] + d1);
    g2lds16(xs0 + k0 + 64, Xh[1] + d0);
    g2lds16(xs1 + k0 + 64, Xh[1] + d1);
    g2lds16(as0 + k0 + 64, Ah[1] + d0);
    g2lds16(as1 + k0 + 64, Ah[1] + d1);
    __syncthreads();
    #pragma unroll
    for (int h = 0; h < 2; ++h) {
      #pragma unroll
      for (int ks = 0; ks < 2; ++ks) {
        const int gk = ks * 4 + quad;
        v8s fa0 = *(v8s*)&Xh[h][(ma0 * 8 + (gk ^ (ma0 & 7))) * 8];
        v8s fa1 = *(v8s*)&Xh[h][(ma1 * 8 + (gk ^ (ma1 & 7))) * 8];
        v8s fb0 = *(v8s*)&Ah[h][(nb0 * 8 + (gk ^ (nb0 & 7))) * 8];
        v8s fb1 = *(v8s*)&Ah[h][(nb1 * 8 + (gk ^ (nb1 & 7))) * 8];
        acc[0][0] = __builtin_amdgcn_mfma_f32_16x16x32_bf16(fa0, fb0, acc[0][0], 0, 0, 0);
        acc[0][1] = __builtin_amdgcn_mfma_f32_16x16x32_bf16(fa0, fb1, acc[0][1], 0, 0, 0);
        acc[1][0] = __builtin_amdgcn_mfma_f32_16x16x32_bf16(fa1, fb0, acc[1][0], 0, 0, 0);
        acc[1][1] = __builtin_amdgcn_mfma_f32_16x16x32_bf16(fa1, fb1, acc[1][1], 0, 0, 0);
      }
    }
  }

  // epilogue: coeff fold + bf16 pack via LDS bounce, 128B-contiguous stores
  __syncthreads();
  uint16_t* tile = S;   // stride 72
  #pragma unroll
  for (int mi = 0; mi < 2; mi++)
    #pragma unroll
    for (int ni = 0; ni < 2; ni++) {
      const int nl = wn + ni * 16 + cl;
      const int eidx = (n0 + nl) >> 4;
      #pragma unroll
      for (int reg = 0; reg < 4; reg++) {
        const int tl = wm + mi * 16 + quad * 4 + reg;
        float wv = acc[mi][ni][reg] * coeffL[tl * 17 + eidx];
        tile[tl * 72 + nl] = f2bf(wv);
      }
    }
  __syncthreads();
  #pragma unroll
  for (int p = 0; p < 2; ++p) {
    const int row  = p * 32 + (tid >> 3);
    const int colg = (tid & 7) * 8;
    uint4 val = *(uint4*)&tile[row * 72 + colg];
    *(uint4*)&wb[(size_t)(m0 + row) * KDIM + n0 + colg] = val;
  }
}

// ---------------------------------------------------------------------------
// K3: gemm_wb, 64x256 tile (acc[2][8]/wave), BK=64 (4 iters), XCD-swizzled,
// two-pass fp32 LDS-bounce epilogue with 1KB-contiguous stores.
// ---------------------------------------------------------------------------
__global__ __launch_bounds__(256) void gemm_wb(
    const uint16_t* __restrict__ wbuf, const uint16_t* __restrict__ Bb,
    float* __restrict__ out) {
  __shared__ uint16_t S[20480];   // 40 KB: Ws 8 KB + Bs 32 KB
  uint16_t* Ws = S;               // 64 rows x 8 granules
  uint16_t* Bs = S + 4096;        // 256 rows x 8 granules
  const int tid  = threadIdx.x;
  const int b    = blockIdx.x;                       // 1024 blocks
  const int m_idx = (b & 7) + ((b >> 6) << 3);       // 0..127
  const int n_idx = (b >> 3) & 7;                    // 0..7
  const int m0 = m_idx * 64;
  const int n0 = n_idx * 256;
  const int lane = tid & 63;
  const int wid  = tid >> 6;
  const int wm   = (wid >> 1) * 32;
  const int wn   = (wid & 1) * 128;
  const int quad = lane >> 4;
  const int cl   = lane & 15;

  // W staging: 512 granules (2/thread)
  const int GW0 = wid * 64 + lane;
  const int GW1 = GW0 + 256;
  const int wr0 = GW0 >> 3, wg0 = (GW0 & 7) ^ (wr0 & 7);
  const int wr1 = GW1 >> 3, wg1 = (GW1 & 7) ^ (wr1 & 7);
  const uint16_t* wsrc0 = wbuf + (size_t)(m0 + wr0) * KDIM + wg0 * 8;
  const uint16_t* wsrc1 = wbuf + (size_t)(m0 + wr1) * KDIM + wg1 * 8;

  // B staging: 2048 granules (8/thread)
  const uint16_t* bsrc[8];
  #pragma unroll
  for (int p = 0; p < 8; ++p) {
    const int G = p * 256 + wid * 64 + lane;
    const int r = G >> 3, g = (G & 7) ^ (r & 7);
    bsrc[p] = Bb + (size_t)(n0 + r) * KDIM + g * 8;
  }

  v4f acc[2][8];
  #pragma unroll
  for (int i = 0; i < 2; i++)
    #pragma unroll
    for (int j = 0; j < 8; j++) acc[i][j] = (v4f){0.f, 0.f, 0.f, 0.f};

  const int ma0 = wm + cl, ma1 = wm + 16 + cl;

  #pragma unroll
  for (int k0 = 0; k0 < KDIM; k0 += 64) {
    __syncthreads();
    g2lds16(wsrc0 + k0, Ws + wid * 512);
    g2lds16(wsrc1 + k0, Ws + wid * 512 + 2048);
    #pragma unroll
    for (int p = 0; p < 8; ++p)
      g2lds16(bsrc[p] + k0, Bs + (p * 256 + wid * 64) * 8);
    __syncthreads();
    #pragma unroll
    for (int ks = 0; ks < 2; ++ks) {
      const int gk = ks * 4 + quad;
      v8s fa0 = *(v8s*)&Ws[(ma0 * 8 + (gk ^ (ma0 & 7))) * 8];
      v8s fa1 = *(v8s*)&Ws[(ma1 * 8 + (gk ^ (ma1 & 7))) * 8];
      v8s fb[8];
      #pragma unroll
      for (int j = 0; j < 8; ++j) {
        const int nb = wn + j * 16 + cl;
        fb[j] = *(v8s*)&Bs[(nb * 8 + (gk ^ (nb & 7))) * 8];
      }
      #pragma unroll
      for (int j = 0; j < 8; ++j) {
        acc[0][j] = __builtin_amdgcn_mfma_f32_16x16x32_bf16(fa0, fb[j], acc[0][j], 0, 0, 0);
        acc[1][j] = __builtin_amdgcn_mfma_f32_16x16x32_bf16(fa1, fb[j], acc[1][j], 0, 0, 0);
      }
    }
  }

  // epilogue: two half-tiles (32 rows each) through fp32 LDS bounce
  float* ft = (float*)S;   // 32 x 260 floats = 33.3 KB <= 40 KB
  #pragma unroll
  for (int h = 0; h < 2; ++h) {
    __syncthreads();
    if ((wid >> 1) == h) {
      #pragma unroll
      for (int mi = 0; mi < 2; mi++)
        #pragma unroll
        for (int j = 0; j < 8; j++) {
          const int col = wn + j * 16 + cl;
          #pragma unroll
          for (int reg = 0; reg < 4; reg++) {
            const int rl = mi * 16 + quad * 4 + reg;   // 0..31
            ft[rl * 260 + col] = acc[mi][j][reg];
          }
        }
    }
    __syncthreads();
    #pragma unroll
    for (int p = 0; p < 8; ++p) {
      const int f4  = p * 256 + tid;     // 0..2047
      const int row = f4 >> 6;           // 0..31
      const int c4  = f4 & 63;
      float4 v = *(float4*)&ft[row * 260 + c4 * 4];
      *(float4*)&out[(size_t)(m0 + h * 32 + row) * O_DIM + n0 + c4 * 4] = v;
    }
  }
}

extern "C" void kernel_launch(void* const* d_in, const int* in_sizes, int n_in,
                              void* d_out, int out_size, void* d_ws, size_t ws_size,
                              hipStream_t stream) {
  (void)in_sizes; (void)n_in; (void)out_size; (void)ws_size;
  const float* x       = (const float*)d_in[0];
  const float* P       = (const float*)d_in[1];
  const float* A       = (const float*)d_in[2];
  const float* Bst     = (const float*)d_in[3];
  const float* scaling = (const float*)d_in[4];
  const int*   topk    = (const int*)d_in[5];
  float* out = (float*)d_out;

  char* ws = (char*)d_ws;
  uint16_t* xb     = (uint16_t*)(ws);                 // 33,554,432 B
  uint16_t* Ab     = (uint16_t*)(ws + 33554432);      //  1,048,576 B
  uint16_t* Bb     = (uint16_t*)(ws + 34603008);      //  1,048,576 B
  uint16_t* wbuf   = (uint16_t*)(ws + 35651584);      //  4,194,304 B
  float4*   parts  = (float4*)  (ws + 39845888);      //  4,194,304 B (no alias)

  hipLaunchKernelGGL(prep_weights, dim3(2048), dim3(256), 0, stream, A, Bst, Ab, Bb);
  hipLaunchKernelGGL(route_stream, dim3(8, 128), dim3(256), 0, stream, x, P, xb, parts);
  hipLaunchKernelGGL(gemm_xa, dim3(512), dim3(256), 0, stream,
                     xb, Ab, parts, scaling, topk, wbuf);
  hipLaunchKernelGGL(gemm_wb, dim3(1024), dim3(256), 0, stream, wbuf, Bb, out);
}